// Round 18
// baseline (147.478 us; speedup 1.0000x reference)
//
#include <hip/hip_runtime.h>
#include <math.h>

#define DEPTH   5
#define HIDDEN  128
#define CODE    400
#define NFREQ   9
#define BATCH   8
#define NPTS    262144
#define PTSB    64
#define BLOCK   256

typedef __attribute__((ext_vector_type(8))) short sh8;
typedef __attribute__((ext_vector_type(4))) float f32x4;
typedef __attribute__((ext_vector_type(4))) uint  u32x4;
typedef __attribute__((ext_vector_type(2))) uint  u32x2;
typedef __bf16 bf16x2 __attribute__((ext_vector_type(2)));

struct CoefTab { float c[54]; };   // [s][yk] SH normalization, host-computed

__device__ __forceinline__ ushort f2bf(float f) {   // round-to-nearest-even
    union { float f; uint u; } v; v.f = f;
    uint r = v.u + 0x7fffu + ((v.u >> 16) & 1u);
    return (ushort)(r >> 16);
}

// ---------------------------------------------------------------------------
// Prep (identical to R16 proven version). wfB and gwB = single RNE bf16
// images.
// ---------------------------------------------------------------------------
__global__ void sinr_prep(const float* __restrict__ a,
                          const float* __restrict__ Wcode,
                          const float* __restrict__ bcode,
                          const float* __restrict__ bfwd,
                          const float* __restrict__ Wftr,
                          const float* __restrict__ bftr,
                          const float* __restrict__ Wfwd,
                          CoefTab ct,
                          float* __restrict__ cterm,
                          ushort* __restrict__ wfB,
                          ushort* __restrict__ gwB) {
    int blk = blockIdx.x, tid = threadIdx.x;
    if (blk < DEPTH * BATCH) {
        if (tid < HIDDEN) {
            int i = blk / BATCH, b = blk % BATCH, h = tid;
            const float* ar = a + b * CODE;
            const float* wr = Wcode + (i * HIDDEN + h) * CODE;
            float acc = bcode[i * HIDDEN + h] + bfwd[i * HIDDEN + h];
            for (int c = 0; c < CODE; c += 4) {
                float4 av = *(const float4*)(ar + c);
                float4 wv = *(const float4*)(wr + c);
                acc = fmaf(av.x, wv.x, acc);
                acc = fmaf(av.y, wv.y, acc);
                acc = fmaf(av.z, wv.z, acc);
                acc = fmaf(av.w, wv.w, acc);
            }
            cterm[(i * BATCH + b) * HIDDEN + h] = acc;
        }
    } else if (blk < DEPTH * BATCH + 96) {
        int e = (blk - DEPTH * BATCH) * BLOCK + tid;     // < 24576
        int j    = e & 7;
        int lane = (e >> 3) & 63;
        int nt   = (e >> 9) & 7;
        int s    = e >> 12;                               // 0..5
        int g  = nt * 16 + (lane & 15);
        int kq = lane >> 4;
        float v = 0.0f;
        if (kq == 0 || kq == 2) {
            v = ct.c[s * 9 + j] * Wftr[(s * HIDDEN + g) * NFREQ + j];
        } else if (kq == 1) {
            if (j == 0 || j == 1)
                v = ct.c[s * 9 + 8] * Wftr[(s * HIDDEN + g) * NFREQ + 8];
            else if (j == 2)
                v = bftr[s * HIDDEN + g];
        }
        wfB[e] = f2bf(v);
    } else {
        int e = (blk - DEPTH * BATCH - 96) * BLOCK + tid;  // < 81920
        if (e < DEPTH * 4 * 8 * 512) {
            int j     = e & 7;
            int lane  = (e >> 3) & 63;
            int nt    = (e >> 9) & 7;
            int kq    = (e >> 12) & 3;
            int layer = e >> 14;
            int g = nt * 16 + (lane & 15);
            int h = kq * 32 + (lane >> 4) * 8 + j;
            gwB[e] = f2bf(Wfwd[(layer * HIDDEN + g) * HIDDEN + h]);
        }
    }
}

// ---------------------------------------------------------------------------
// Main. vs R17 (neutral; 72.4 us R16-proven): pure-scheduling change —
// manual depth-2 software pipeline, registers budgeted under the proven
// bound-4 cap (64 arch + 16 pipeline + 32 acc ~= 112 <= 128):
//  * kq loop: prefetch kq+1's two gwB B-fragments (nb0/nb1) during kq's
//    MFMAs (explicit copy-swap, +8 VGPRs) — hides the ~200cyc L2 latency
//    that unroll-1 serialized (unroll-1 itself stays: it prevents the
//    4-deep hoist that spilled in R8).
//  * epilogue wfB load hoisted BEFORE the kq loop (+8 VGPRs): ~500cyc of
//    latency hidden under the kq MFMAs instead of serial after the loop.
// R17 lesson recorded: the 3.54M SQ_LDS_BANK_CONFLICT is structural to
// wave64 b128/b64 access widths (row stride 256B = 2 bank wraps; l15&7
// already 2-way-free) — not a fixable conflict; swizzle-key kept (neutral).
// ---------------------------------------------------------------------------
__global__ __launch_bounds__(BLOCK, 4)
void sinr_main(const float* __restrict__ x,
               const ushort* __restrict__ wfB,
               const ushort* __restrict__ gwB,
               const float* __restrict__ cterm,
               const float* __restrict__ Wout,
               const float* __restrict__ boutp,
               float* __restrict__ out,
               float* __restrict__ out_x) {
    __shared__ __align__(16) ushort zA[PTSB * HIDDEN];      // 16 KB
    __shared__ __align__(16) ushort zB[PTSB * HIDDEN];      // 16 KB
    __shared__ __align__(16) ushort ypk[2 * 3 * PTSB * 8];  // 6 KB (dbuf)
    __shared__ __align__(16) ushort zrow[8];

    const int tid  = threadIdx.x;
    const int lane = tid & 63;
    const int w    = tid >> 6;
    const int l15  = lane & 15, lq = lane >> 4;
    const int p0   = blockIdx.x * PTSB;
    const int b    = p0 >> 15;

    // swizzle key for this lane's rows (row&15 == l15 everywhere below)
    const int zkey = l15 ^ ((l15 & 8) >> 1);

    if (tid < 2 * PTSB) out_x[p0 * 2 + tid] = x[p0 * 2 + tid];
    if (tid < 8) zrow[tid] = 0;

    // staged pre-packed shift (wave w owns shift: w==0->4, 1->5, 2->2, 3->3)
    sh8 pk0, pk2;
    uint pk1w = 0;   // k1[0] | k1[1]<<16 (rest of k1 is constant)

    // store one packed shift triple into ypk buffer `buf`
    auto ystore = [&](int buf, const sh8& k0, const sh8& k1, const sh8& k2) {
        int off = (buf * 3 * PTSB + lane) * 8;
        *(sh8*)&ypk[off]                = k0;
        *(sh8*)&ypk[off + PTSB * 8]     = k1;
        *(sh8*)&ypk[off + 2 * PTSB * 8] = k2;
    };

    // ---- harmonics: every wave computes the full proven P/trig table ------
    {
        float th = x[(p0 + lane) * 2 + 0];
        float ph = x[(p0 + lane) * 2 + 1];
        float c  = cosf(ph);
        float somx2 = sqrtf(fmaxf(1.0f - c * c, 0.0f));
        float s1, c1;
        sincosf(th, &s1, &c1);
        float ctab[5], stab[5];
        ctab[0] = 1.0f; stab[0] = 0.0f;
        ctab[1] = c1;   stab[1] = s1;
#pragma unroll
        for (int k = 2; k <= 4; ++k) {
            ctab[k] = ctab[k - 1] * c1 - stab[k - 1] * s1;
            stab[k] = stab[k - 1] * c1 + ctab[k - 1] * s1;
        }
        float P[5][6];
        float pmm = 1.0f;
#pragma unroll
        for (int am = 0; am <= 4; ++am) {
            if (am > 0) pmm *= -(2.0f * am - 1.0f) * somx2;
            float pm2 = pmm;
            float pm1 = c * (2.0f * am + 1.0f) * pmm;
            P[am][0] = pm2;
            P[am][1] = pm1;
#pragma unroll
            for (int s = 2; s < 6; ++s) {
                int l = am + s;
                // divisor (l-am) == s is an unroll-time constant: multiply by
                // the folded reciprocal (s=2,4 exact; s=3,5 <=1 ulp on P —
                // invisible after bf16 rounding; proven R12/R14).
                float pl = ((2.0f * l - 1.0f) * c * pm1
                            - (float)(l + am - 1) * pm2) * (1.0f / (float)s);
                P[am][s] = pl;
                pm2 = pm1;
                pm1 = pl;
            }
        }
        // verbatim proven pack loop, parameterized by the 5 P values
        auto mk = [&](float Pv0, float Pv1, float Pv2, float Pv3, float Pv4,
                      sh8& k0, sh8& k1, sh8& k2) {
            float Pv[5] = {Pv0, Pv1, Pv2, Pv3, Pv4};
            ushort yh[9], yl[9];
#pragma unroll
            for (int mm = -4; mm <= 4; ++mm) {
                int am = mm < 0 ? -mm : mm;
                float trig = (mm > 0) ? ctab[am] : ((mm < 0) ? stab[am] : 1.0f);
                float yv = Pv[am] * trig;
                uint u = __float_as_uint(yv);
                yh[mm + 4] = (ushort)(u >> 16);
                float rf = yv - __uint_as_float(u & 0xFFFF0000u);
                yl[mm + 4] = (ushort)(__float_as_uint(rf) >> 16);
            }
#pragma unroll
            for (int j = 0; j < 8; ++j) { k0[j] = (short)yh[j]; k2[j] = (short)yl[j]; }
            k1[0] = (short)yh[8]; k1[1] = (short)yl[8]; k1[2] = (short)0x3F80;
            k1[3] = 0; k1[4] = 0; k1[5] = 0; k1[6] = 0; k1[7] = 0;
        };
        sh8 t0, t1, t2;
        if (w == 0) {
            mk(P[0][0], P[1][0], P[2][0], P[3][0], P[4][0], t0, t1, t2);
            ystore(0, t0, t1, t2);
            mk(P[0][4], P[1][4], P[2][4], P[3][4], P[4][4], pk0, t1, pk2);
            pk1w = (uint)(ushort)t1[0] | ((uint)(ushort)t1[1] << 16);
        } else if (w == 1) {
            mk(P[0][1], P[1][1], P[2][1], P[3][1], P[4][1], t0, t1, t2);
            ystore(1, t0, t1, t2);
            mk(P[0][5], P[1][5], P[2][5], P[3][5], P[4][5], pk0, t1, pk2);
            pk1w = (uint)(ushort)t1[0] | ((uint)(ushort)t1[1] << 16);
        } else if (w == 2) {
            mk(P[0][2], P[1][2], P[2][2], P[3][2], P[4][2], pk0, t1, pk2);
            pk1w = (uint)(ushort)t1[0] | ((uint)(ushort)t1[1] << 16);
        } else {
            mk(P[0][3], P[1][3], P[2][3], P[3][3], P[4][3], pk0, t1, pk2);
            pk1w = (uint)(ushort)t1[0] | ((uint)(ushort)t1[1] << 16);
        }
    }
    __syncthreads();

    // z store into buffer zbuf, TRANSPOSED fragment: lane holds point row =
    // mt*16+l15 and 4 consecutive h = (w*2+nt)*16 + lq*4 + r; one b64 write.
    auto zstore4 = [&](ushort* zbuf, int mt, int nt, f32x4 t) {
        int row = mt * 16 + l15;
        int ch  = (w * 2 + nt) * 2 + (lq >> 1);
        int idx = row * HIDDEN + ((ch ^ zkey) << 3) + (lq & 1) * 4;
        bf16x2 pa = {(__bf16)t[0], (__bf16)t[1]};
        bf16x2 pb = {(__bf16)t[2], (__bf16)t[3]};
        u32x2 pv;
        pv.x = __builtin_bit_cast(uint, pa);
        pv.y = __builtin_bit_cast(uint, pb);
        *(u32x2*)&zbuf[idx] = pv;
    };

    // ---- z init: z0 = F(sft=0) -> zA, single-image filter, 1 MFMA ---------
    {
        sh8 wb[2];
#pragma unroll
        for (int nt = 0; nt < 2; ++nt)
            wb[nt] = *(const sh8*)(wfB + 0 * 4096 + (w * 2 + nt) * 512 + lane * 8);
#pragma unroll
        for (int mt = 0; mt < 4; ++mt) {
            const ushort* ya = (lq < 3)
                ? &ypk[((0 * 3 + lq) * PTSB + mt * 16 + l15) * 8]
                : &zrow[0];
            sh8 yf = *(const sh8*)ya;
#pragma unroll
            for (int nt = 0; nt < 2; ++nt) {
                f32x4 t = (f32x4){0.f, 0.f, 0.f, 0.f};
                t = __builtin_amdgcn_mfma_f32_16x16x32_bf16(wb[nt], yf, t, 0, 0, 0);
                zstore4(zA, mt, nt, t);
            }
        }
    }
    __syncthreads();

    // ---- 5 layers (ONE barrier per layer; z ping-pong) ---------------------
    for (int layer = 0; layer < DEPTH; ++layer) {
        ushort* zin  = (layer & 1) ? zB : zA;
        ushort* zout = (layer & 1) ? zA : zB;

        // publish shift layer+2 into ypk buffer (layer+2)&1 (proven schedule).
        if (layer < DEPTH - 1 && w == ((layer + 2) & 3)) {
            sh8 k1;
            k1[0] = (short)(ushort)(pk1w & 0xFFFFu);
            k1[1] = (short)(ushort)(pk1w >> 16);
            k1[2] = (short)0x3F80;
            k1[3] = 0; k1[4] = 0; k1[5] = 0; k1[6] = 0; k1[7] = 0;
            ystore((layer + 2) & 1, pk0, k1, pk2);
        }

        // HOISTED epilogue filter load: issued here, consumed after the kq
        // loop — latency hidden under the MFMAs. +8 VGPRs across the loop.
        sh8 fwb[2];
#pragma unroll
        for (int nt = 0; nt < 2; ++nt)
            fwb[nt] = *(const sh8*)(wfB + (layer + 1) * 4096
                                    + (w * 2 + nt) * 512 + lane * 8);

        f32x4 acc[4][2];
#pragma unroll
        for (int mt = 0; mt < 4; ++mt)
#pragma unroll
            for (int nt = 0; nt < 2; ++nt)
                acc[mt][nt] = (f32x4){0.f, 0.f, 0.f, 0.f};

        // Depth-2 software-pipelined kq loop: prefetch kq+1's B-fragments
        // while kq's MFMAs run. unroll-1 stays (prevents R8's 4-deep spill).
        const ushort* gp0 = gwB + (layer * 4) * 4096 + lane * 8;
        sh8 nb0 = *(const sh8*)(gp0 + (w * 2 + 0) * 512);
        sh8 nb1 = *(const sh8*)(gp0 + (w * 2 + 1) * 512);
#pragma unroll 1
        for (int kq = 0; kq < 4; ++kq) {
            sh8 bh0 = nb0;
            sh8 bh1 = nb1;
            if (kq < 3) {
                const ushort* gn = gwB + (layer * 4 + kq + 1) * 4096 + lane * 8;
                nb0 = *(const sh8*)(gn + (w * 2 + 0) * 512);
                nb1 = *(const sh8*)(gn + (w * 2 + 1) * 512);
            }
#pragma unroll
            for (int mt = 0; mt < 4; ++mt) {
                int row  = mt * 16 + l15;
                int base = row * HIDDEN + (((kq * 4 + lq) ^ zkey) << 3);
                sh8 ah = *(const sh8*)&zin[base];
                acc[mt][0] = __builtin_amdgcn_mfma_f32_16x16x32_bf16(bh0, ah, acc[mt][0], 0, 0, 0);
                acc[mt][1] = __builtin_amdgcn_mfma_f32_16x16x32_bf16(bh1, ah, acc[mt][1], 0, 0, 0);
            }
        }
        // NO barrier here: epilogue writes zout (the OTHER buffer) — no WAR.

        // ctv: per nt, 4 consecutive cterm values at h = (w*2+nt)*16 + lq*4
        f32x4 ctv[2];
#pragma unroll
        for (int nt = 0; nt < 2; ++nt)
            ctv[nt] = *(const f32x4*)&cterm[(layer * BATCH + b) * HIDDEN
                                            + (w * 2 + nt) * 16 + lq * 4];

        // fused F phase + epilogue, per mt: z_next = (acc + ct) * F -> zout.
        // fwb already in registers (loaded before the kq loop).
        {
#pragma unroll
            for (int mt = 0; mt < 4; ++mt) {
                const ushort* ya = (lq < 3)
                    ? &ypk[((((layer + 1) & 1) * 3 + lq) * PTSB + mt * 16 + l15) * 8]
                    : &zrow[0];
                sh8 yf = *(const sh8*)ya;
#pragma unroll
                for (int nt = 0; nt < 2; ++nt) {
                    f32x4 t = (f32x4){0.f, 0.f, 0.f, 0.f};
                    t = __builtin_amdgcn_mfma_f32_16x16x32_bf16(fwb[nt], yf, t, 0, 0, 0);
                    f32x4 vv;
#pragma unroll
                    for (int r = 0; r < 4; ++r)
                        vv[r] = (acc[mt][nt][r] + ctv[nt][r]) * t[r];
                    zstore4(zout, mt, nt, vv);
                }
            }
        }
        __syncthreads();   // zout visible before next layer's reads
    }

    // ---- final: out[p] = z · Wout + bout; z is in zB (layer 4 wrote it) ----
    float* psum = (float*)ypk;
    {
        int p = lane, qd = w;
        int fkey = (p & 15) ^ ((p & 8) >> 1);   // same key, row = p
        float accf = 0.0f;
#pragma unroll
        for (int cc = 0; cc < 4; ++cc) {
            int chunk = qd * 4 + cc;
            int base  = p * HIDDEN + ((chunk ^ fkey) << 3);
            u32x4 hv = *(const u32x4*)&zB[base];
            uint uh[4] = {hv.x, hv.y, hv.z, hv.w};
            const float* wp = Wout + chunk * 8;
#pragma unroll
            for (int q2 = 0; q2 < 4; ++q2) {
                float a0 = __uint_as_float(uh[q2] << 16);
                float a1 = __uint_as_float(uh[q2] & 0xFFFF0000u);
                accf = fmaf(a0, wp[q2 * 2], accf);
                accf = fmaf(a1, wp[q2 * 2 + 1], accf);
            }
        }
        psum[qd * 64 + p] = accf;
    }
    __syncthreads();
    if (tid < PTSB) {
        out[p0 + tid] = boutp[0] + psum[tid] + psum[64 + tid]
                                 + psum[128 + tid] + psum[192 + tid];
    }
}

// ---------------------------------------------------------------------------
extern "C" void kernel_launch(void* const* d_in, const int* in_sizes, int n_in,
                              void* d_out, int out_size, void* d_ws, size_t ws_size,
                              hipStream_t stream) {
    (void)in_sizes; (void)n_in; (void)out_size; (void)ws_size;
    const float* x     = (const float*)d_in[0];
    const float* a     = (const float*)d_in[1];
    const float* Wftr  = (const float*)d_in[2];
    const float* bftr  = (const float*)d_in[3];
    const float* Wfwd  = (const float*)d_in[4];
    const float* bfwd  = (const float*)d_in[5];
    const float* Wcode = (const float*)d_in[6];
    const float* bcode = (const float*)d_in[7];
    const float* Wout  = (const float*)d_in[8];
    const float* bout  = (const float*)d_in[9];

    float* out   = (float*)d_out;                    // [B*N]
    float* out_x = out + NPTS;                       // [B*N*2]
    float*  cterm = (float*)d_ws;                    // 5120 floats
    ushort* wfB = (ushort*)(cterm + DEPTH * BATCH * HIDDEN);  // 24576 ushorts
    ushort* gwB = wfB + 24576;                                // 81920 ushorts

    // SH normalization coefficients on host (deterministic per call)
    CoefTab ct;
    for (int s = 0; s < 6; ++s)
        for (int yk = 0; yk < 9; ++yk) {
            int mm = yk - 4, am = mm < 0 ? -mm : mm, l = am + s;
            double ratio = 1.0;
            for (int q = l - am + 1; q <= l + am; ++q) ratio *= (double)q;
            double norm = sqrt((2.0 * l + 1.0) / (4.0 * M_PI * ratio));
            double cf = (mm == 0) ? norm : ((am & 1) ? -1.0 : 1.0) * sqrt(2.0) * norm;
            ct.c[s * 9 + yk] = (float)cf;
        }

    int nprep = DEPTH * BATCH + 96 + 320;
    sinr_prep<<<nprep, BLOCK, 0, stream>>>(a, Wcode, bcode, bfwd, Wftr, bftr,
                                           Wfwd, ct, cterm, wfB, gwB);
    sinr_main<<<NPTS / PTSB, BLOCK, 0, stream>>>(
        x, wfB, gwB, cterm, Wout, bout, out, out_x);
}

// Round 19
// 140.174 us; speedup vs baseline: 1.0521x; 1.0521x over previous
//
#include <hip/hip_runtime.h>
#include <math.h>

#define DEPTH   5
#define HIDDEN  128
#define CODE    400
#define NFREQ   9
#define BATCH   8
#define NPTS    262144
#define PTSB    64
#define BLOCK   256

typedef __attribute__((ext_vector_type(8))) short sh8;
typedef __attribute__((ext_vector_type(4))) float f32x4;
typedef __attribute__((ext_vector_type(4))) uint  u32x4;
typedef __attribute__((ext_vector_type(2))) uint  u32x2;
typedef __bf16 bf16x2 __attribute__((ext_vector_type(2)));

struct CoefTab { float c[54]; };   // [s][yk] SH normalization, host-computed

__device__ __forceinline__ ushort f2bf(float f) {   // round-to-nearest-even
    union { float f; uint u; } v; v.f = f;
    uint r = v.u + 0x7fffu + ((v.u >> 16) & 1u);
    return (ushort)(r >> 16);
}

// ---------------------------------------------------------------------------
// Prep (identical to R16 proven version). wfB and gwB = single RNE bf16
// images.
// ---------------------------------------------------------------------------
__global__ void sinr_prep(const float* __restrict__ a,
                          const float* __restrict__ Wcode,
                          const float* __restrict__ bcode,
                          const float* __restrict__ bfwd,
                          const float* __restrict__ Wftr,
                          const float* __restrict__ bftr,
                          const float* __restrict__ Wfwd,
                          CoefTab ct,
                          float* __restrict__ cterm,
                          ushort* __restrict__ wfB,
                          ushort* __restrict__ gwB) {
    int blk = blockIdx.x, tid = threadIdx.x;
    if (blk < DEPTH * BATCH) {
        if (tid < HIDDEN) {
            int i = blk / BATCH, b = blk % BATCH, h = tid;
            const float* ar = a + b * CODE;
            const float* wr = Wcode + (i * HIDDEN + h) * CODE;
            float acc = bcode[i * HIDDEN + h] + bfwd[i * HIDDEN + h];
            for (int c = 0; c < CODE; c += 4) {
                float4 av = *(const float4*)(ar + c);
                float4 wv = *(const float4*)(wr + c);
                acc = fmaf(av.x, wv.x, acc);
                acc = fmaf(av.y, wv.y, acc);
                acc = fmaf(av.z, wv.z, acc);
                acc = fmaf(av.w, wv.w, acc);
            }
            cterm[(i * BATCH + b) * HIDDEN + h] = acc;
        }
    } else if (blk < DEPTH * BATCH + 96) {
        int e = (blk - DEPTH * BATCH) * BLOCK + tid;     // < 24576
        int j    = e & 7;
        int lane = (e >> 3) & 63;
        int nt   = (e >> 9) & 7;
        int s    = e >> 12;                               // 0..5
        int g  = nt * 16 + (lane & 15);
        int kq = lane >> 4;
        float v = 0.0f;
        if (kq == 0 || kq == 2) {
            v = ct.c[s * 9 + j] * Wftr[(s * HIDDEN + g) * NFREQ + j];
        } else if (kq == 1) {
            if (j == 0 || j == 1)
                v = ct.c[s * 9 + 8] * Wftr[(s * HIDDEN + g) * NFREQ + 8];
            else if (j == 2)
                v = bftr[s * HIDDEN + g];
        }
        wfB[e] = f2bf(v);
    } else {
        int e = (blk - DEPTH * BATCH - 96) * BLOCK + tid;  // < 81920
        if (e < DEPTH * 4 * 8 * 512) {
            int j     = e & 7;
            int lane  = (e >> 3) & 63;
            int nt    = (e >> 9) & 7;
            int kq    = (e >> 12) & 3;
            int layer = e >> 14;
            int g = nt * 16 + (lane & 15);
            int h = kq * 32 + (lane >> 4) * 8 + j;
            gwB[e] = f2bf(Wfwd[(layer * HIDDEN + g) * HIDDEN + h]);
        }
    }
}

// ---------------------------------------------------------------------------
// Main. vs R17/R16 (72.4 us proven; R18's manual pipeline reverted — it was
// neutral, compiler already schedules those loads): the FINAL OUT-PROJECTION
// IS FUSED into layer 4's epilogue. Previously layer 4 rounded z to bf16,
// stored 8xb64, barriered, re-read 8xb128, re-expanded, and dotted with
// Wout. Now: each thread folds sum(vv * Wout[h]) into the epilogue (same
// fma count as the removed final phase), reduces the 4 lq-contributors per
// row with two __shfl_xor (16,32), and lq==0 lanes write a [4 waves][64
// rows] psum (256 floats) overlaying ypk buffer 0 — dead since layer 3's
// barrier (shift-4's last read); shift-5 reads are in buffer 1, disjoint.
// Removes/thread: 32 f2bf + 8 b64 st + 8 b128 ld + 32 fma + 1 barrier.
// Numerics: dot uses UNROUNDED f32 z (closer to ref); sum order changes
// (within-thread -> lq-shuffle -> wave sum) — error still ~f32-dot level.
// ---------------------------------------------------------------------------
__global__ __launch_bounds__(BLOCK, 4)
void sinr_main(const float* __restrict__ x,
               const ushort* __restrict__ wfB,
               const ushort* __restrict__ gwB,
               const float* __restrict__ cterm,
               const float* __restrict__ Wout,
               const float* __restrict__ boutp,
               float* __restrict__ out,
               float* __restrict__ out_x) {
    __shared__ __align__(16) ushort zA[PTSB * HIDDEN];      // 16 KB
    __shared__ __align__(16) ushort zB[PTSB * HIDDEN];      // 16 KB
    __shared__ __align__(16) ushort ypk[2 * 3 * PTSB * 8];  // 6 KB (dbuf)
    __shared__ __align__(16) ushort zrow[8];

    const int tid  = threadIdx.x;
    const int lane = tid & 63;
    const int w    = tid >> 6;
    const int l15  = lane & 15, lq = lane >> 4;
    const int p0   = blockIdx.x * PTSB;
    const int b    = p0 >> 15;

    // swizzle key for this lane's rows (row&15 == l15 everywhere below)
    const int zkey = l15 ^ ((l15 & 8) >> 1);

    if (tid < 2 * PTSB) out_x[p0 * 2 + tid] = x[p0 * 2 + tid];
    if (tid < 8) zrow[tid] = 0;

    // staged pre-packed shift (wave w owns shift: w==0->4, 1->5, 2->2, 3->3)
    sh8 pk0, pk2;
    uint pk1w = 0;   // k1[0] | k1[1]<<16 (rest of k1 is constant)

    // store one packed shift triple into ypk buffer `buf`
    auto ystore = [&](int buf, const sh8& k0, const sh8& k1, const sh8& k2) {
        int off = (buf * 3 * PTSB + lane) * 8;
        *(sh8*)&ypk[off]                = k0;
        *(sh8*)&ypk[off + PTSB * 8]     = k1;
        *(sh8*)&ypk[off + 2 * PTSB * 8] = k2;
    };

    // ---- harmonics: every wave computes the full proven P/trig table ------
    {
        float th = x[(p0 + lane) * 2 + 0];
        float ph = x[(p0 + lane) * 2 + 1];
        float c  = cosf(ph);
        float somx2 = sqrtf(fmaxf(1.0f - c * c, 0.0f));
        float s1, c1;
        sincosf(th, &s1, &c1);
        float ctab[5], stab[5];
        ctab[0] = 1.0f; stab[0] = 0.0f;
        ctab[1] = c1;   stab[1] = s1;
#pragma unroll
        for (int k = 2; k <= 4; ++k) {
            ctab[k] = ctab[k - 1] * c1 - stab[k - 1] * s1;
            stab[k] = stab[k - 1] * c1 + ctab[k - 1] * s1;
        }
        float P[5][6];
        float pmm = 1.0f;
#pragma unroll
        for (int am = 0; am <= 4; ++am) {
            if (am > 0) pmm *= -(2.0f * am - 1.0f) * somx2;
            float pm2 = pmm;
            float pm1 = c * (2.0f * am + 1.0f) * pmm;
            P[am][0] = pm2;
            P[am][1] = pm1;
#pragma unroll
            for (int s = 2; s < 6; ++s) {
                int l = am + s;
                // divisor (l-am) == s is an unroll-time constant: multiply by
                // the folded reciprocal (s=2,4 exact; s=3,5 <=1 ulp on P —
                // invisible after bf16 rounding; proven R12/R14).
                float pl = ((2.0f * l - 1.0f) * c * pm1
                            - (float)(l + am - 1) * pm2) * (1.0f / (float)s);
                P[am][s] = pl;
                pm2 = pm1;
                pm1 = pl;
            }
        }
        // verbatim proven pack loop, parameterized by the 5 P values
        auto mk = [&](float Pv0, float Pv1, float Pv2, float Pv3, float Pv4,
                      sh8& k0, sh8& k1, sh8& k2) {
            float Pv[5] = {Pv0, Pv1, Pv2, Pv3, Pv4};
            ushort yh[9], yl[9];
#pragma unroll
            for (int mm = -4; mm <= 4; ++mm) {
                int am = mm < 0 ? -mm : mm;
                float trig = (mm > 0) ? ctab[am] : ((mm < 0) ? stab[am] : 1.0f);
                float yv = Pv[am] * trig;
                uint u = __float_as_uint(yv);
                yh[mm + 4] = (ushort)(u >> 16);
                float rf = yv - __uint_as_float(u & 0xFFFF0000u);
                yl[mm + 4] = (ushort)(__float_as_uint(rf) >> 16);
            }
#pragma unroll
            for (int j = 0; j < 8; ++j) { k0[j] = (short)yh[j]; k2[j] = (short)yl[j]; }
            k1[0] = (short)yh[8]; k1[1] = (short)yl[8]; k1[2] = (short)0x3F80;
            k1[3] = 0; k1[4] = 0; k1[5] = 0; k1[6] = 0; k1[7] = 0;
        };
        sh8 t0, t1, t2;
        if (w == 0) {
            mk(P[0][0], P[1][0], P[2][0], P[3][0], P[4][0], t0, t1, t2);
            ystore(0, t0, t1, t2);
            mk(P[0][4], P[1][4], P[2][4], P[3][4], P[4][4], pk0, t1, pk2);
            pk1w = (uint)(ushort)t1[0] | ((uint)(ushort)t1[1] << 16);
        } else if (w == 1) {
            mk(P[0][1], P[1][1], P[2][1], P[3][1], P[4][1], t0, t1, t2);
            ystore(1, t0, t1, t2);
            mk(P[0][5], P[1][5], P[2][5], P[3][5], P[4][5], pk0, t1, pk2);
            pk1w = (uint)(ushort)t1[0] | ((uint)(ushort)t1[1] << 16);
        } else if (w == 2) {
            mk(P[0][2], P[1][2], P[2][2], P[3][2], P[4][2], pk0, t1, pk2);
            pk1w = (uint)(ushort)t1[0] | ((uint)(ushort)t1[1] << 16);
        } else {
            mk(P[0][3], P[1][3], P[2][3], P[3][3], P[4][3], pk0, t1, pk2);
            pk1w = (uint)(ushort)t1[0] | ((uint)(ushort)t1[1] << 16);
        }
    }
    __syncthreads();

    // z store into buffer zbuf, TRANSPOSED fragment: lane holds point row =
    // mt*16+l15 and 4 consecutive h = (w*2+nt)*16 + lq*4 + r; one b64 write.
    auto zstore4 = [&](ushort* zbuf, int mt, int nt, f32x4 t) {
        int row = mt * 16 + l15;
        int ch  = (w * 2 + nt) * 2 + (lq >> 1);
        int idx = row * HIDDEN + ((ch ^ zkey) << 3) + (lq & 1) * 4;
        bf16x2 pa = {(__bf16)t[0], (__bf16)t[1]};
        bf16x2 pb = {(__bf16)t[2], (__bf16)t[3]};
        u32x2 pv;
        pv.x = __builtin_bit_cast(uint, pa);
        pv.y = __builtin_bit_cast(uint, pb);
        *(u32x2*)&zbuf[idx] = pv;
    };

    // ---- z init: z0 = F(sft=0) -> zA, single-image filter, 1 MFMA ---------
    {
        sh8 wb[2];
#pragma unroll
        for (int nt = 0; nt < 2; ++nt)
            wb[nt] = *(const sh8*)(wfB + 0 * 4096 + (w * 2 + nt) * 512 + lane * 8);
#pragma unroll
        for (int mt = 0; mt < 4; ++mt) {
            const ushort* ya = (lq < 3)
                ? &ypk[((0 * 3 + lq) * PTSB + mt * 16 + l15) * 8]
                : &zrow[0];
            sh8 yf = *(const sh8*)ya;
#pragma unroll
            for (int nt = 0; nt < 2; ++nt) {
                f32x4 t = (f32x4){0.f, 0.f, 0.f, 0.f};
                t = __builtin_amdgcn_mfma_f32_16x16x32_bf16(wb[nt], yf, t, 0, 0, 0);
                zstore4(zA, mt, nt, t);
            }
        }
    }
    __syncthreads();

    // ---- 5 layers (ONE barrier per layer; z ping-pong; last layer fuses
    //      the out-projection) ----------------------------------------------
    for (int layer = 0; layer < DEPTH; ++layer) {
        ushort* zin  = (layer & 1) ? zB : zA;
        ushort* zout = (layer & 1) ? zA : zB;
        const bool last = (layer == DEPTH - 1);

        // publish shift layer+2 into ypk buffer (layer+2)&1 (proven schedule).
        if (layer < DEPTH - 1 && w == ((layer + 2) & 3)) {
            sh8 k1;
            k1[0] = (short)(ushort)(pk1w & 0xFFFFu);
            k1[1] = (short)(ushort)(pk1w >> 16);
            k1[2] = (short)0x3F80;
            k1[3] = 0; k1[4] = 0; k1[5] = 0; k1[6] = 0; k1[7] = 0;
            ystore((layer + 2) & 1, pk0, k1, pk2);
        }

        f32x4 acc[4][2];
#pragma unroll
        for (int mt = 0; mt < 4; ++mt)
#pragma unroll
            for (int nt = 0; nt < 2; ++nt)
                acc[mt][nt] = (f32x4){0.f, 0.f, 0.f, 0.f};

        // NOT unrolled: full unroll hoists all 4 kq iterations' B-frag loads
        // which spills under the bound-4 128-reg budget (R8 lesson).
#pragma unroll 1
        for (int kq = 0; kq < 4; ++kq) {
            // single rounded-bf16 Wfwd image: [layer][kq][nt][lane][j]
            const ushort* gp = gwB + (layer * 4 + kq) * 4096 + lane * 8;
            sh8 bh0 = *(const sh8*)(gp + (w * 2 + 0) * 512);
            sh8 bh1 = *(const sh8*)(gp + (w * 2 + 1) * 512);
#pragma unroll
            for (int mt = 0; mt < 4; ++mt) {
                int row  = mt * 16 + l15;
                int base = row * HIDDEN + (((kq * 4 + lq) ^ zkey) << 3);
                sh8 ah = *(const sh8*)&zin[base];
                acc[mt][0] = __builtin_amdgcn_mfma_f32_16x16x32_bf16(bh0, ah, acc[mt][0], 0, 0, 0);
                acc[mt][1] = __builtin_amdgcn_mfma_f32_16x16x32_bf16(bh1, ah, acc[mt][1], 0, 0, 0);
            }
        }
        // NO barrier here: epilogue writes zout (the OTHER buffer) — no WAR.

        // ctv: per nt, 4 consecutive cterm values at h = (w*2+nt)*16 + lq*4
        f32x4 ctv[2];
#pragma unroll
        for (int nt = 0; nt < 2; ++nt)
            ctv[nt] = *(const f32x4*)&cterm[(layer * BATCH + b) * HIDDEN
                                            + (w * 2 + nt) * 16 + lq * 4];

        // fused F phase + epilogue, per mt: z_next = (acc + ct) * F.
        // Non-last layers: -> zout. Last layer: fold the out-projection.
        {
            sh8 wb[2];
#pragma unroll
            for (int nt = 0; nt < 2; ++nt)
                wb[nt] = *(const sh8*)(wfB + (layer + 1) * 4096
                                       + (w * 2 + nt) * 512 + lane * 8);
            f32x4 wo[2];
            if (last) {
#pragma unroll
                for (int nt = 0; nt < 2; ++nt)
                    wo[nt] = *(const f32x4*)&Wout[(w * 2 + nt) * 16 + lq * 4];
            }
            float part[4] = {0.f, 0.f, 0.f, 0.f};
#pragma unroll
            for (int mt = 0; mt < 4; ++mt) {
                const ushort* ya = (lq < 3)
                    ? &ypk[((((layer + 1) & 1) * 3 + lq) * PTSB + mt * 16 + l15) * 8]
                    : &zrow[0];
                sh8 yf = *(const sh8*)ya;
#pragma unroll
                for (int nt = 0; nt < 2; ++nt) {
                    f32x4 t = (f32x4){0.f, 0.f, 0.f, 0.f};
                    t = __builtin_amdgcn_mfma_f32_16x16x32_bf16(wb[nt], yf, t, 0, 0, 0);
                    f32x4 vv;
#pragma unroll
                    for (int r = 0; r < 4; ++r)
                        vv[r] = (acc[mt][nt][r] + ctv[nt][r]) * t[r];
                    if (!last) {
                        zstore4(zout, mt, nt, vv);
                    } else {
#pragma unroll
                        for (int r = 0; r < 4; ++r)
                            part[mt] = fmaf(vv[r], wo[nt][r], part[mt]);
                    }
                }
            }
            if (last) {
                // reduce the 4 lq-contributors per row; psum overlays ypk
                // buffer 0 (dead since layer-3's barrier; shift-5 reads are
                // in buffer 1, disjoint addresses).
                float* psum = (float*)ypk;
#pragma unroll
                for (int mt = 0; mt < 4; ++mt) {
                    float v = part[mt];
                    v += __shfl_xor(v, 16, 64);
                    v += __shfl_xor(v, 32, 64);
                    if (lq == 0) psum[w * 64 + mt * 16 + l15] = v;
                }
            }
        }
        __syncthreads();   // zout (or psum) visible
    }

    // ---- final: out[p] = bout + sum over the 4 wave-partials ---------------
    if (tid < PTSB) {
        float* psum = (float*)ypk;
        out[p0 + tid] = boutp[0] + psum[tid] + psum[64 + tid]
                                 + psum[128 + tid] + psum[192 + tid];
    }
}

// ---------------------------------------------------------------------------
extern "C" void kernel_launch(void* const* d_in, const int* in_sizes, int n_in,
                              void* d_out, int out_size, void* d_ws, size_t ws_size,
                              hipStream_t stream) {
    (void)in_sizes; (void)n_in; (void)out_size; (void)ws_size;
    const float* x     = (const float*)d_in[0];
    const float* a     = (const float*)d_in[1];
    const float* Wftr  = (const float*)d_in[2];
    const float* bftr  = (const float*)d_in[3];
    const float* Wfwd  = (const float*)d_in[4];
    const float* bfwd  = (const float*)d_in[5];
    const float* Wcode = (const float*)d_in[6];
    const float* bcode = (const float*)d_in[7];
    const float* Wout  = (const float*)d_in[8];
    const float* bout  = (const float*)d_in[9];

    float* out   = (float*)d_out;                    // [B*N]
    float* out_x = out + NPTS;                       // [B*N*2]
    float*  cterm = (float*)d_ws;                    // 5120 floats
    ushort* wfB = (ushort*)(cterm + DEPTH * BATCH * HIDDEN);  // 24576 ushorts
    ushort* gwB = wfB + 24576;                                // 81920 ushorts

    // SH normalization coefficients on host (deterministic per call)
    CoefTab ct;
    for (int s = 0; s < 6; ++s)
        for (int yk = 0; yk < 9; ++yk) {
            int mm = yk - 4, am = mm < 0 ? -mm : mm, l = am + s;
            double ratio = 1.0;
            for (int q = l - am + 1; q <= l + am; ++q) ratio *= (double)q;
            double norm = sqrt((2.0 * l + 1.0) / (4.0 * M_PI * ratio));
            double cf = (mm == 0) ? norm : ((am & 1) ? -1.0 : 1.0) * sqrt(2.0) * norm;
            ct.c[s * 9 + yk] = (float)cf;
        }

    int nprep = DEPTH * BATCH + 96 + 320;
    sinr_prep<<<nprep, BLOCK, 0, stream>>>(a, Wcode, bcode, bfwd, Wftr, bftr,
                                           Wfwd, ct, cterm, wfB, gwB);
    sinr_main<<<NPTS / PTSB, BLOCK, 0, stream>>>(
        x, wfB, gwB, cterm, Wout, bout, out, out_x);
}

// Round 20
// 140.171 us; speedup vs baseline: 1.0521x; 1.0000x over previous
//
#include <hip/hip_runtime.h>
#include <math.h>

#define DEPTH   5
#define HIDDEN  128
#define CODE    400
#define NFREQ   9
#define BATCH   8
#define NPTS    262144
#define PTSB    64
#define BLOCK   256

typedef __attribute__((ext_vector_type(8))) short sh8;
typedef __attribute__((ext_vector_type(4))) float f32x4;
typedef __attribute__((ext_vector_type(4))) uint  u32x4;
typedef __attribute__((ext_vector_type(2))) uint  u32x2;
typedef __bf16 bf16x2 __attribute__((ext_vector_type(2)));

struct CoefTab { float c[54]; };   // [s][yk] SH normalization, host-computed

__device__ __forceinline__ ushort f2bf(float f) {   // round-to-nearest-even
    union { float f; uint u; } v; v.f = f;
    uint r = v.u + 0x7fffu + ((v.u >> 16) & 1u);
    return (ushort)(r >> 16);
}

// ---------------------------------------------------------------------------
// Prep (identical to R16/R19 proven version). wfB and gwB = single RNE bf16
// images.
// ---------------------------------------------------------------------------
__global__ void sinr_prep(const float* __restrict__ a,
                          const float* __restrict__ Wcode,
                          const float* __restrict__ bcode,
                          const float* __restrict__ bfwd,
                          const float* __restrict__ Wftr,
                          const float* __restrict__ bftr,
                          const float* __restrict__ Wfwd,
                          CoefTab ct,
                          float* __restrict__ cterm,
                          ushort* __restrict__ wfB,
                          ushort* __restrict__ gwB) {
    int blk = blockIdx.x, tid = threadIdx.x;
    if (blk < DEPTH * BATCH) {
        if (tid < HIDDEN) {
            int i = blk / BATCH, b = blk % BATCH, h = tid;
            const float* ar = a + b * CODE;
            const float* wr = Wcode + (i * HIDDEN + h) * CODE;
            float acc = bcode[i * HIDDEN + h] + bfwd[i * HIDDEN + h];
            for (int c = 0; c < CODE; c += 4) {
                float4 av = *(const float4*)(ar + c);
                float4 wv = *(const float4*)(wr + c);
                acc = fmaf(av.x, wv.x, acc);
                acc = fmaf(av.y, wv.y, acc);
                acc = fmaf(av.z, wv.z, acc);
                acc = fmaf(av.w, wv.w, acc);
            }
            cterm[(i * BATCH + b) * HIDDEN + h] = acc;
        }
    } else if (blk < DEPTH * BATCH + 96) {
        int e = (blk - DEPTH * BATCH) * BLOCK + tid;     // < 24576
        int j    = e & 7;
        int lane = (e >> 3) & 63;
        int nt   = (e >> 9) & 7;
        int s    = e >> 12;                               // 0..5
        int g  = nt * 16 + (lane & 15);
        int kq = lane >> 4;
        float v = 0.0f;
        if (kq == 0 || kq == 2) {
            v = ct.c[s * 9 + j] * Wftr[(s * HIDDEN + g) * NFREQ + j];
        } else if (kq == 1) {
            if (j == 0 || j == 1)
                v = ct.c[s * 9 + 8] * Wftr[(s * HIDDEN + g) * NFREQ + 8];
            else if (j == 2)
                v = bftr[s * HIDDEN + g];
        }
        wfB[e] = f2bf(v);
    } else {
        int e = (blk - DEPTH * BATCH - 96) * BLOCK + tid;  // < 81920
        if (e < DEPTH * 4 * 8 * 512) {
            int j     = e & 7;
            int lane  = (e >> 3) & 63;
            int nt    = (e >> 9) & 7;
            int kq    = (e >> 12) & 3;
            int layer = e >> 14;
            int g = nt * 16 + (lane & 15);
            int h = kq * 32 + (lane >> 4) * 8 + j;
            gwB[e] = f2bf(Wfwd[(layer * HIDDEN + g) * HIDDEN + h]);
        }
    }
}

// ---------------------------------------------------------------------------
// Main. vs R19 (68.2 us proven): two free VALU cuts, schedule untouched:
//  * acc initialized to ctv instead of 0: the epilogue's (acc+ctv) add is
//    deleted (32 v_add x 5 layers / thread). Same init instruction count
//    (32 movs vs 32 zero-writes); ctv regs die right after the copy -> no
//    pressure change across the kq loop. fp32 reorder only (ctv+Sum vs
//    Sum+ctv) — noise far below the bf16 output ulp.
//  * Per-wave truncated Legendre recurrence: wave w needs shifts {w, w+4}
//    only -> guard recurrence steps with wave-uniform s<=smax (4,5,2,3).
//    Compile-time P indices preserved (no dynamic-index scratch risk).
// ---------------------------------------------------------------------------
__global__ __launch_bounds__(BLOCK, 4)
void sinr_main(const float* __restrict__ x,
               const ushort* __restrict__ wfB,
               const ushort* __restrict__ gwB,
               const float* __restrict__ cterm,
               const float* __restrict__ Wout,
               const float* __restrict__ boutp,
               float* __restrict__ out,
               float* __restrict__ out_x) {
    __shared__ __align__(16) ushort zA[PTSB * HIDDEN];      // 16 KB
    __shared__ __align__(16) ushort zB[PTSB * HIDDEN];      // 16 KB
    __shared__ __align__(16) ushort ypk[2 * 3 * PTSB * 8];  // 6 KB (dbuf)
    __shared__ __align__(16) ushort zrow[8];

    const int tid  = threadIdx.x;
    const int lane = tid & 63;
    const int w    = tid >> 6;
    const int l15  = lane & 15, lq = lane >> 4;
    const int p0   = blockIdx.x * PTSB;
    const int b    = p0 >> 15;

    // swizzle key for this lane's rows (row&15 == l15 everywhere below)
    const int zkey = l15 ^ ((l15 & 8) >> 1);

    if (tid < 2 * PTSB) out_x[p0 * 2 + tid] = x[p0 * 2 + tid];
    if (tid < 8) zrow[tid] = 0;

    // staged pre-packed shift (wave w owns shift: w==0->4, 1->5, 2->2, 3->3)
    sh8 pk0, pk2;
    uint pk1w = 0;   // k1[0] | k1[1]<<16 (rest of k1 is constant)

    // store one packed shift triple into ypk buffer `buf`
    auto ystore = [&](int buf, const sh8& k0, const sh8& k1, const sh8& k2) {
        int off = (buf * 3 * PTSB + lane) * 8;
        *(sh8*)&ypk[off]                = k0;
        *(sh8*)&ypk[off + PTSB * 8]     = k1;
        *(sh8*)&ypk[off + 2 * PTSB * 8] = k2;
    };

    // ---- harmonics: per-wave truncated P/trig table ------------------------
    {
        float th = x[(p0 + lane) * 2 + 0];
        float ph = x[(p0 + lane) * 2 + 1];
        float c  = cosf(ph);
        float somx2 = sqrtf(fmaxf(1.0f - c * c, 0.0f));
        float s1, c1;
        sincosf(th, &s1, &c1);
        float ctab[5], stab[5];
        ctab[0] = 1.0f; stab[0] = 0.0f;
        ctab[1] = c1;   stab[1] = s1;
#pragma unroll
        for (int k = 2; k <= 4; ++k) {
            ctab[k] = ctab[k - 1] * c1 - stab[k - 1] * s1;
            stab[k] = stab[k - 1] * c1 + ctab[k - 1] * s1;
        }
        // wave w needs shifts {w, w+4} only -> recurrence depth smax
        const int smax = (w == 0) ? 4 : (w == 1) ? 5 : (w == 2) ? 2 : 3;
        float P[5][6];
        float pmm = 1.0f;
#pragma unroll
        for (int am = 0; am <= 4; ++am) {
            if (am > 0) pmm *= -(2.0f * am - 1.0f) * somx2;
            float pm2 = pmm;
            float pm1 = c * (2.0f * am + 1.0f) * pmm;
            P[am][0] = pm2;
            P[am][1] = pm1;
#pragma unroll
            for (int s = 2; s < 6; ++s) {
                if (s <= smax) {
                    int l = am + s;
                    // reciprocal-multiply (proven R12/R14): s=2,4 exact;
                    // s=3,5 <=1 ulp on P, invisible after bf16 rounding.
                    float pl = ((2.0f * l - 1.0f) * c * pm1
                                - (float)(l + am - 1) * pm2) * (1.0f / (float)s);
                    P[am][s] = pl;
                    pm2 = pm1;
                    pm1 = pl;
                }
            }
        }
        // verbatim proven pack loop, parameterized by the 5 P values
        auto mk = [&](float Pv0, float Pv1, float Pv2, float Pv3, float Pv4,
                      sh8& k0, sh8& k1, sh8& k2) {
            float Pv[5] = {Pv0, Pv1, Pv2, Pv3, Pv4};
            ushort yh[9], yl[9];
#pragma unroll
            for (int mm = -4; mm <= 4; ++mm) {
                int am = mm < 0 ? -mm : mm;
                float trig = (mm > 0) ? ctab[am] : ((mm < 0) ? stab[am] : 1.0f);
                float yv = Pv[am] * trig;
                uint u = __float_as_uint(yv);
                yh[mm + 4] = (ushort)(u >> 16);
                float rf = yv - __uint_as_float(u & 0xFFFF0000u);
                yl[mm + 4] = (ushort)(__float_as_uint(rf) >> 16);
            }
#pragma unroll
            for (int j = 0; j < 8; ++j) { k0[j] = (short)yh[j]; k2[j] = (short)yl[j]; }
            k1[0] = (short)yh[8]; k1[1] = (short)yl[8]; k1[2] = (short)0x3F80;
            k1[3] = 0; k1[4] = 0; k1[5] = 0; k1[6] = 0; k1[7] = 0;
        };
        sh8 t0, t1, t2;
        if (w == 0) {
            mk(P[0][0], P[1][0], P[2][0], P[3][0], P[4][0], t0, t1, t2);
            ystore(0, t0, t1, t2);
            mk(P[0][4], P[1][4], P[2][4], P[3][4], P[4][4], pk0, t1, pk2);
            pk1w = (uint)(ushort)t1[0] | ((uint)(ushort)t1[1] << 16);
        } else if (w == 1) {
            mk(P[0][1], P[1][1], P[2][1], P[3][1], P[4][1], t0, t1, t2);
            ystore(1, t0, t1, t2);
            mk(P[0][5], P[1][5], P[2][5], P[3][5], P[4][5], pk0, t1, pk2);
            pk1w = (uint)(ushort)t1[0] | ((uint)(ushort)t1[1] << 16);
        } else if (w == 2) {
            mk(P[0][2], P[1][2], P[2][2], P[3][2], P[4][2], pk0, t1, pk2);
            pk1w = (uint)(ushort)t1[0] | ((uint)(ushort)t1[1] << 16);
        } else {
            mk(P[0][3], P[1][3], P[2][3], P[3][3], P[4][3], pk0, t1, pk2);
            pk1w = (uint)(ushort)t1[0] | ((uint)(ushort)t1[1] << 16);
        }
    }
    __syncthreads();

    // z store into buffer zbuf, TRANSPOSED fragment: lane holds point row =
    // mt*16+l15 and 4 consecutive h = (w*2+nt)*16 + lq*4 + r; one b64 write.
    auto zstore4 = [&](ushort* zbuf, int mt, int nt, f32x4 t) {
        int row = mt * 16 + l15;
        int ch  = (w * 2 + nt) * 2 + (lq >> 1);
        int idx = row * HIDDEN + ((ch ^ zkey) << 3) + (lq & 1) * 4;
        bf16x2 pa = {(__bf16)t[0], (__bf16)t[1]};
        bf16x2 pb = {(__bf16)t[2], (__bf16)t[3]};
        u32x2 pv;
        pv.x = __builtin_bit_cast(uint, pa);
        pv.y = __builtin_bit_cast(uint, pb);
        *(u32x2*)&zbuf[idx] = pv;
    };

    // ---- z init: z0 = F(sft=0) -> zA, single-image filter, 1 MFMA ---------
    {
        sh8 wb[2];
#pragma unroll
        for (int nt = 0; nt < 2; ++nt)
            wb[nt] = *(const sh8*)(wfB + 0 * 4096 + (w * 2 + nt) * 512 + lane * 8);
#pragma unroll
        for (int mt = 0; mt < 4; ++mt) {
            const ushort* ya = (lq < 3)
                ? &ypk[((0 * 3 + lq) * PTSB + mt * 16 + l15) * 8]
                : &zrow[0];
            sh8 yf = *(const sh8*)ya;
#pragma unroll
            for (int nt = 0; nt < 2; ++nt) {
                f32x4 t = (f32x4){0.f, 0.f, 0.f, 0.f};
                t = __builtin_amdgcn_mfma_f32_16x16x32_bf16(wb[nt], yf, t, 0, 0, 0);
                zstore4(zA, mt, nt, t);
            }
        }
    }
    __syncthreads();

    // ---- 5 layers (ONE barrier per layer; z ping-pong; last layer fuses
    //      the out-projection) ----------------------------------------------
    for (int layer = 0; layer < DEPTH; ++layer) {
        ushort* zin  = (layer & 1) ? zB : zA;
        ushort* zout = (layer & 1) ? zA : zB;
        const bool last = (layer == DEPTH - 1);

        // publish shift layer+2 into ypk buffer (layer+2)&1 (proven schedule).
        if (layer < DEPTH - 1 && w == ((layer + 2) & 3)) {
            sh8 k1;
            k1[0] = (short)(ushort)(pk1w & 0xFFFFu);
            k1[1] = (short)(ushort)(pk1w >> 16);
            k1[2] = (short)0x3F80;
            k1[3] = 0; k1[4] = 0; k1[5] = 0; k1[6] = 0; k1[7] = 0;
            ystore((layer + 2) & 1, pk0, k1, pk2);
        }

        // ctv: per nt, 4 consecutive cterm values at h = (w*2+nt)*16 + lq*4.
        // Used ONLY to seed acc (dies right after) — no pressure across loop.
        f32x4 ctv[2];
#pragma unroll
        for (int nt = 0; nt < 2; ++nt)
            ctv[nt] = *(const f32x4*)&cterm[(layer * BATCH + b) * HIDDEN
                                            + (w * 2 + nt) * 16 + lq * 4];

        // acc seeded with ctv: epilogue's (acc+ctv) add is gone.
        f32x4 acc[4][2];
#pragma unroll
        for (int mt = 0; mt < 4; ++mt)
#pragma unroll
            for (int nt = 0; nt < 2; ++nt)
                acc[mt][nt] = ctv[nt];

        // NOT unrolled: full unroll hoists all 4 kq iterations' B-frag loads
        // which spills under the bound-4 128-reg budget (R8 lesson).
#pragma unroll 1
        for (int kq = 0; kq < 4; ++kq) {
            // single rounded-bf16 Wfwd image: [layer][kq][nt][lane][j]
            const ushort* gp = gwB + (layer * 4 + kq) * 4096 + lane * 8;
            sh8 bh0 = *(const sh8*)(gp + (w * 2 + 0) * 512);
            sh8 bh1 = *(const sh8*)(gp + (w * 2 + 1) * 512);
#pragma unroll
            for (int mt = 0; mt < 4; ++mt) {
                int row  = mt * 16 + l15;
                int base = row * HIDDEN + (((kq * 4 + lq) ^ zkey) << 3);
                sh8 ah = *(const sh8*)&zin[base];
                acc[mt][0] = __builtin_amdgcn_mfma_f32_16x16x32_bf16(bh0, ah, acc[mt][0], 0, 0, 0);
                acc[mt][1] = __builtin_amdgcn_mfma_f32_16x16x32_bf16(bh1, ah, acc[mt][1], 0, 0, 0);
            }
        }
        // NO barrier here: epilogue writes zout (the OTHER buffer) — no WAR.

        // fused F phase + epilogue, per mt: z_next = acc * F (ctv folded in).
        // Non-last layers: -> zout. Last layer: fold the out-projection.
        {
            sh8 wb[2];
#pragma unroll
            for (int nt = 0; nt < 2; ++nt)
                wb[nt] = *(const sh8*)(wfB + (layer + 1) * 4096
                                       + (w * 2 + nt) * 512 + lane * 8);
            f32x4 wo[2];
            if (last) {
#pragma unroll
                for (int nt = 0; nt < 2; ++nt)
                    wo[nt] = *(const f32x4*)&Wout[(w * 2 + nt) * 16 + lq * 4];
            }
            float part[4] = {0.f, 0.f, 0.f, 0.f};
#pragma unroll
            for (int mt = 0; mt < 4; ++mt) {
                const ushort* ya = (lq < 3)
                    ? &ypk[((((layer + 1) & 1) * 3 + lq) * PTSB + mt * 16 + l15) * 8]
                    : &zrow[0];
                sh8 yf = *(const sh8*)ya;
#pragma unroll
                for (int nt = 0; nt < 2; ++nt) {
                    f32x4 t = (f32x4){0.f, 0.f, 0.f, 0.f};
                    t = __builtin_amdgcn_mfma_f32_16x16x32_bf16(wb[nt], yf, t, 0, 0, 0);
                    f32x4 vv;
#pragma unroll
                    for (int r = 0; r < 4; ++r)
                        vv[r] = acc[mt][nt][r] * t[r];
                    if (!last) {
                        zstore4(zout, mt, nt, vv);
                    } else {
#pragma unroll
                        for (int r = 0; r < 4; ++r)
                            part[mt] = fmaf(vv[r], wo[nt][r], part[mt]);
                    }
                }
            }
            if (last) {
                // reduce the 4 lq-contributors per row; psum overlays ypk
                // buffer 0 (dead since layer-3's barrier; shift-5 reads are
                // in buffer 1, disjoint addresses).
                float* psum = (float*)ypk;
#pragma unroll
                for (int mt = 0; mt < 4; ++mt) {
                    float v = part[mt];
                    v += __shfl_xor(v, 16, 64);
                    v += __shfl_xor(v, 32, 64);
                    if (lq == 0) psum[w * 64 + mt * 16 + l15] = v;
                }
            }
        }
        __syncthreads();   // zout (or psum) visible
    }

    // ---- final: out[p] = bout + sum over the 4 wave-partials ---------------
    if (tid < PTSB) {
        float* psum = (float*)ypk;
        out[p0 + tid] = boutp[0] + psum[tid] + psum[64 + tid]
                                 + psum[128 + tid] + psum[192 + tid];
    }
}

// ---------------------------------------------------------------------------
extern "C" void kernel_launch(void* const* d_in, const int* in_sizes, int n_in,
                              void* d_out, int out_size, void* d_ws, size_t ws_size,
                              hipStream_t stream) {
    (void)in_sizes; (void)n_in; (void)out_size; (void)ws_size;
    const float* x     = (const float*)d_in[0];
    const float* a     = (const float*)d_in[1];
    const float* Wftr  = (const float*)d_in[2];
    const float* bftr  = (const float*)d_in[3];
    const float* Wfwd  = (const float*)d_in[4];
    const float* bfwd  = (const float*)d_in[5];
    const float* Wcode = (const float*)d_in[6];
    const float* bcode = (const float*)d_in[7];
    const float* Wout  = (const float*)d_in[8];
    const float* bout  = (const float*)d_in[9];

    float* out   = (float*)d_out;                    // [B*N]
    float* out_x = out + NPTS;                       // [B*N*2]
    float*  cterm = (float*)d_ws;                    // 5120 floats
    ushort* wfB = (ushort*)(cterm + DEPTH * BATCH * HIDDEN);  // 24576 ushorts
    ushort* gwB = wfB + 24576;                                // 81920 ushorts

    // SH normalization coefficients on host (deterministic per call)
    CoefTab ct;
    for (int s = 0; s < 6; ++s)
        for (int yk = 0; yk < 9; ++yk) {
            int mm = yk - 4, am = mm < 0 ? -mm : mm, l = am + s;
            double ratio = 1.0;
            for (int q = l - am + 1; q <= l + am; ++q) ratio *= (double)q;
            double norm = sqrt((2.0 * l + 1.0) / (4.0 * M_PI * ratio));
            double cf = (mm == 0) ? norm : ((am & 1) ? -1.0 : 1.0) * sqrt(2.0) * norm;
            ct.c[s * 9 + yk] = (float)cf;
        }

    int nprep = DEPTH * BATCH + 96 + 320;
    sinr_prep<<<nprep, BLOCK, 0, stream>>>(a, Wcode, bcode, bfwd, Wftr, bftr,
                                           Wfwd, ct, cterm, wfB, gwB);
    sinr_main<<<NPTS / PTSB, BLOCK, 0, stream>>>(
        x, wfB, gwB, cterm, Wout, bout, out, out_x);
}